// Round 7
// baseline (562.738 us; speedup 1.0000x reference)
//
#include <hip/hip_runtime.h>

#define NE 500000      // edges
#define ND 50000       // nodes
#define DIMK 256       // embedding dim
#define H1 128
#define H2 64
#define EPSBN 1e-5f
#define NT 1954        // tiles of 256 edges
#define NTN 196        // node tiles of 256 rows
#define GE 512         // k_edge grid
#define GS 512         // k_stats grid
#define G2 1024        // k_layer2 grid

typedef _Float16 half8 __attribute__((ext_vector_type(8)));
typedef float f32x4 __attribute__((ext_vector_type(4)));
typedef unsigned short ushort8 __attribute__((ext_vector_type(8)));

static __device__ __forceinline__ half8 habs8(half8 x) {
  ushort8 u = __builtin_bit_cast(ushort8, x);
  u &= (unsigned short)0x7FFF;
  return __builtin_bit_cast(half8, u);
}
static __device__ __forceinline__ half8 hrelu8(half8 x) {
  half8 r;
#pragma unroll
  for (int j = 0; j < 8; ++j) r[j] = x[j] > (_Float16)0 ? x[j] : (_Float16)0;
  return r;
}
static __device__ __forceinline__ float h2f(unsigned int u) {
  return (float)__builtin_bit_cast(_Float16, (unsigned short)(u & 0xffff));
}

// c0[j] = b1[j] + step @ W1[768:800, j]
__global__ void k_prep(const float* __restrict__ W1, const float* __restrict__ b1,
                       const float* __restrict__ step, float* __restrict__ c0) {
  const int j = threadIdx.x;
  if (j < H1) {
    float a = b1[j];
#pragma unroll
    for (int tt = 0; tt < 32; ++tt) a += step[tt] * W1[(768 + tt) * H1 + j];
    c0[j] = a;
  }
}

// fp32 emb -> fp16
__global__ void k_prep16(const float* __restrict__ emb, _Float16* __restrict__ embh) {
  const int i = (blockIdx.x * 256 + threadIdx.x) * 8;
  const float4 a = *(const float4*)(emb + i);
  const float4 b = *(const float4*)(emb + i + 4);
  half8 h;
  h[0] = (_Float16)a.x; h[1] = (_Float16)a.y; h[2] = (_Float16)a.z; h[3] = (_Float16)a.w;
  h[4] = (_Float16)b.x; h[5] = (_Float16)b.y; h[6] = (_Float16)b.z; h[7] = (_Float16)b.w;
  *(half8*)(embh + i) = h;
}

// frag-ordered C-segment (W1 rows 512..768), K=256, N=128: f = kc*8+c
__global__ void k_prepBC(const float* __restrict__ W1, _Float16* __restrict__ bfragC) {
  const int g = blockIdx.x * 256 + threadIdx.x;   // < 4096
  const int lane = g & 63, f = g >> 6;
  const int c = f & 7, kc = f >> 3;
  const int row0 = 512 + kc * 32 + (lane >> 4) * 8;
  const int col = c * 16 + (lane & 15);
  half8 h;
#pragma unroll
  for (int j = 0; j < 8; ++j) h[j] = (_Float16)W1[(row0 + j) * H1 + col];
  *(half8*)(bfragC + (size_t)g * 8) = h;
}

// frag-ordered node-B: cols 0..127 = W1[0:256] (A), 128..255 = W1[256:512] (B)
__global__ void k_prepBN(const float* __restrict__ W1, _Float16* __restrict__ bfragN) {
  const int g = blockIdx.x * 256 + threadIdx.x;   // < 8192
  const int lane = g & 63, f = g >> 6;            // f = kc*16 + c, c in [0,16)
  const int c = f & 15, kc = f >> 4;
  const int k0 = kc * 32 + (lane >> 4) * 8;
  const int colg = c * 16 + (lane & 15);
  half8 h;
#pragma unroll
  for (int j = 0; j < 8; ++j) {
    const int k = k0 + j;
    h[j] = (_Float16)((colg < 128) ? W1[k * H1 + colg] : W1[(256 + k) * H1 + (colg - 128)]);
  }
  *(half8*)(bfragN + (size_t)g * 8) = h;
}

// PQ = embh @ [A|B]  (50000 x 256). grid = NTN*4; block: one (tile, col-quarter).
__global__ __launch_bounds__(256, 2)
void k_node(const _Float16* __restrict__ embh, const _Float16* __restrict__ bfragN,
            _Float16* __restrict__ PQ) {
  __shared__ __align__(16) _Float16 lB[16384];   // 32 KB quarter
  const int t = threadIdx.x, bid = blockIdx.x;
  const int ch = bid & 3, tile = bid >> 2;
  const int w = t >> 6, lane = t & 63, quad = lane >> 4, m15 = lane & 15;
  {
    half8* lb = (half8*)lB; const half8* gb = (const half8*)bfragN;
    for (int i = t; i < 2048; i += 256) {
      const int li = i & 63, fl = i >> 6;        // fl = kc*4 + c
      const int c = fl & 3, kc = fl >> 2;
      lb[i] = gb[(size_t)((kc * 16 + ch * 4 + c) * 64 + li)];
    }
  }
  __syncthreads();
  const int base = tile * 256;
  const _Float16* pa[4];
#pragma unroll
  for (int r = 0; r < 4; ++r) {
    int n = base + w * 64 + r * 16 + m15; if (n >= ND) n = ND - 1;
    pa[r] = embh + (size_t)n * DIMK + quad * 8;
  }
  f32x4 acc[4][4];
#pragma unroll
  for (int r = 0; r < 4; ++r)
#pragma unroll
    for (int c = 0; c < 4; ++c) acc[r][c] = (f32x4)0.f;
  const half8* lb = (const half8*)lB;
#pragma unroll 1
  for (int kc = 0; kc < 8; ++kc) {
    half8 a[4];
#pragma unroll
    for (int r = 0; r < 4; ++r) a[r] = *(const half8*)(pa[r] + kc * 32);
#pragma unroll
    for (int c = 0; c < 4; ++c) {
      const half8 bf = lb[(kc * 4 + c) * 64 + lane];
#pragma unroll
      for (int r = 0; r < 4; ++r)
        acc[r][c] = __builtin_amdgcn_mfma_f32_16x16x32_f16(a[r], bf, acc[r][c], 0, 0, 0);
    }
  }
#pragma unroll
  for (int r = 0; r < 4; ++r) {
    const int nrow = base + w * 64 + r * 16 + quad * 4;
#pragma unroll
    for (int c = 0; c < 4; ++c) {
      const int col = ch * 64 + c * 16 + m15;
#pragma unroll
      for (int reg = 0; reg < 4; ++reg) {
        const int n = nrow + reg;
        if (n < ND) PQ[(size_t)n * 256 + col] = (_Float16)acc[r][c][reg];
      }
    }
  }
}

// E = |u-v|@C + g*wg + c0   (pre-ReLU edge part, fp16 row-major 128)
// 512 thr: 8 waves = 4 row-groups x 2 col-halves (col-halves share u/v via L1).
__global__ __launch_bounds__(512, 4)
void k_edge(const _Float16* __restrict__ embh, const void* __restrict__ eidx_raw,
            const float* __restrict__ grad, const float* __restrict__ W1,
            const float* __restrict__ c0, const _Float16* __restrict__ bfragC,
            _Float16* __restrict__ E) {
  __shared__ __align__(16) _Float16 lB[32768];   // 64 KB, full C-seg frag order
  __shared__ int s_src[256], s_dst[256];
  __shared__ float s_g[256];
  __shared__ float s_wg[128], s_c0[128];
  const int t = threadIdx.x, bid = blockIdx.x;
  const int w = t >> 6, lane = t & 63, quad = lane >> 4, m15 = lane & 15;
  const int rw = w & 3, cw = w >> 2;
  {
    half8* lb = (half8*)lB; const half8* gb = (const half8*)bfragC;
    for (int i = t; i < 4096; i += 512) lb[i] = gb[i];
  }
  if (t < 128) { s_wg[t] = W1[800 * H1 + t]; s_c0[t] = c0[t]; }

  const unsigned* ew = (const unsigned*)eidx_raw;
  const bool is64 = ((ew[1] | ew[3] | ew[5] | ew[7]) == 0u);
  const int* e32 = (const int*)eidx_raw;
  const long long* e64 = (const long long*)eidx_raw;
  const half8* lb = (const half8*)lB;

  for (int tile = bid; tile < NT; tile += GE) {
    const int base = tile * 256;
    __syncthreads();
    if (t < 256) {
      int e = base + t; if (e >= NE) e = NE - 1;
      if (is64) { s_src[t] = (int)e64[e]; s_dst[t] = (int)e64[NE + e]; }
      else      { s_src[t] = e32[e];      s_dst[t] = e32[NE + e]; }
      s_g[t] = grad[e];
    }
    __syncthreads();

    const _Float16* pu[4];
    const _Float16* pv[4];
#pragma unroll
    for (int r = 0; r < 4; ++r) {
      const int row = rw * 64 + r * 16 + m15;
      pu[r] = embh + (size_t)s_src[row] * DIMK + quad * 8;
      pv[r] = embh + (size_t)s_dst[row] * DIMK + quad * 8;
    }
    f32x4 acc[4][4];
#pragma unroll
    for (int r = 0; r < 4; ++r)
#pragma unroll
      for (int c = 0; c < 4; ++c) acc[r][c] = (f32x4)0.f;

#pragma unroll 1
    for (int kc = 0; kc < 8; ++kc) {
      half8 d[4];
#pragma unroll
      for (int r = 0; r < 4; ++r) {
        const half8 u = *(const half8*)(pu[r] + kc * 32);
        const half8 v = *(const half8*)(pv[r] + kc * 32);
        d[r] = habs8(u - v);
      }
#pragma unroll
      for (int c = 0; c < 4; ++c) {
        const half8 bd = lb[(kc * 8 + cw * 4 + c) * 64 + lane];
#pragma unroll
        for (int r = 0; r < 4; ++r)
          acc[r][c] = __builtin_amdgcn_mfma_f32_16x16x32_f16(d[r], bd, acc[r][c], 0, 0, 0);
      }
    }
#pragma unroll
    for (int r = 0; r < 4; ++r) {
      const int erow = rw * 64 + r * 16 + quad * 4;
#pragma unroll
      for (int c = 0; c < 4; ++c) {
        const int colL = cw * 64 + c * 16 + m15;
        const float wgv = s_wg[colL], c0v = s_c0[colL];
#pragma unroll
        for (int reg = 0; reg < 4; ++reg) {
          const int e = base + erow + reg;
          const float x = acc[r][c][reg] + s_g[erow + reg] * wgv + c0v;
          if (e < NE) E[(size_t)e * H1 + colL] = (_Float16)x;
        }
      }
    }
  }
}

// BN1 stats over relu(E + P[src] + Q[dst]) without materializing x1
__global__ __launch_bounds__(256, 4)
void k_stats(const _Float16* __restrict__ E, const _Float16* __restrict__ PQ,
             const void* __restrict__ eidx_raw, float* __restrict__ p1) {
  __shared__ float s_sum[128], s_sq[128];
  const int t = threadIdx.x, bid = blockIdx.x;
  const int cg = t & 15, el = t >> 4;
  if (t < 128) { s_sum[t] = 0.f; s_sq[t] = 0.f; }
  __syncthreads();
  const unsigned* ew = (const unsigned*)eidx_raw;
  const bool is64 = ((ew[1] | ew[3] | ew[5] | ew[7]) == 0u);
  const int* e32 = (const int*)eidx_raw;
  const long long* e64 = (const long long*)eidx_raw;
  float s8[8] = {0, 0, 0, 0, 0, 0, 0, 0}, q8[8] = {0, 0, 0, 0, 0, 0, 0, 0};
  for (int e = bid * 16 + el; e < NE; e += GS * 16) {
    int sr, dr;
    if (is64) { sr = (int)e64[e]; dr = (int)e64[NE + e]; }
    else      { sr = e32[e];      dr = e32[NE + e]; }
    const half8 E8 = *(const half8*)(E + (size_t)e * H1 + cg * 8);
    const half8 P8 = *(const half8*)(PQ + (size_t)sr * 256 + cg * 8);
    const half8 Q8 = *(const half8*)(PQ + (size_t)dr * 256 + 128 + cg * 8);
    const half8 x = E8 + P8 + Q8;
#pragma unroll
    for (int j = 0; j < 8; ++j) {
      const float xf = fmaxf((float)x[j], 0.f);
      s8[j] += xf; q8[j] += xf * xf;
    }
  }
#pragma unroll
  for (int j = 0; j < 8; ++j) {
    atomicAdd(&s_sum[cg * 8 + j], s8[j]);
    atomicAdd(&s_sq[cg * 8 + j], q8[j]);
  }
  __syncthreads();
  if (t < 128) {
    p1[t * GS + bid] = s_sum[t];
    p1[128 * GS + t * GS + bid] = s_sq[t];
  }
}

// Finalize BN1 stats, fold into W2/b2
__global__ void k_fin1(const float* __restrict__ p1, const float* __restrict__ g1,
                       const float* __restrict__ be1, const float* __restrict__ W2,
                       const float* __restrict__ b2, float* __restrict__ w2f,
                       float* __restrict__ b2f) {
  __shared__ float s1[128], t1[128];
  const int t = threadIdx.x;
  if (t < 128) {
    float s = 0.f, q = 0.f;
    const float4* rs = (const float4*)(p1 + t * GS);
    const float4* rq = (const float4*)(p1 + 128 * GS + t * GS);
#pragma unroll 4
    for (int i = 0; i < GS / 4; ++i) {
      float4 a = rs[i]; s += a.x + a.y + a.z + a.w;
      float4 b = rq[i]; q += b.x + b.y + b.z + b.w;
    }
    const float inv = 1.0f / (float)NE;
    float mean = s * inv;
    float var = q * inv - mean * mean;
    float sc = g1[t] * rsqrtf(var + EPSBN);
    s1[t] = sc; t1[t] = be1[t] - mean * sc;
  }
  __syncthreads();
  for (int i = t; i < H1 * H2; i += 256) w2f[i] = s1[i >> 6] * W2[i];
  if (t < 64) {
    float b = b2[t];
    for (int j = 0; j < 128; ++j) b += t1[j] * W2[j * 64 + t];
    b2f[t] = b;
  }
}

// Layer 2: A = relu(E + P[src] + Q[dst]) built inline; x2 in-place into E rows
__global__ __launch_bounds__(256, 4)
void k_layer2(_Float16* __restrict__ E, const _Float16* __restrict__ PQ,
              const void* __restrict__ eidx_raw, const float* __restrict__ w2f,
              const float* __restrict__ b2f, float* __restrict__ p2) {
  __shared__ __align__(16) _Float16 b_lds[8192];
  __shared__ int s_src[256], s_dst[256];
  __shared__ float s_b[64], s_sum[64], s_sq[64];
  const int t = threadIdx.x, bid = blockIdx.x;
  const int w = t >> 6, lane = t & 63, quad = lane >> 4, m15 = lane & 15;

  for (int i = t; i < 8192; i += 256) {
    const int j = i & 7, li = (i >> 3) & 63, f = i >> 9;
    const int c = f & 3, kk = f >> 2;
    const int row = kk * 32 + (li >> 4) * 8 + j;
    const int col = c * 16 + (li & 15);
    b_lds[i] = (_Float16)w2f[row * H2 + col];
  }
  if (t < 64) { s_b[t] = b2f[t]; s_sum[t] = 0.f; s_sq[t] = 0.f; }

  const unsigned* ew = (const unsigned*)eidx_raw;
  const bool is64 = ((ew[1] | ew[3] | ew[5] | ew[7]) == 0u);
  const int* e32 = (const int*)eidx_raw;
  const long long* e64 = (const long long*)eidx_raw;

  float st_s[4] = {0, 0, 0, 0}, st_q[4] = {0, 0, 0, 0};
  const half8* bp = (const half8*)b_lds;

  for (int job = bid; job < NT; job += G2) {
    const int base = job * 256;
    __syncthreads();
    if (t < 256) {
      int e = base + t; if (e >= NE) e = NE - 1;
      if (is64) { s_src[t] = (int)e64[e]; s_dst[t] = (int)e64[NE + e]; }
      else      { s_src[t] = e32[e];      s_dst[t] = e32[NE + e]; }
    }
    __syncthreads();

    const _Float16* pe[4];
    const _Float16* ps[4];
    const _Float16* pq[4];
#pragma unroll
    for (int r = 0; r < 4; ++r) {
      const int row = w * 64 + r * 16 + m15;
      int e = base + row; if (e >= NE) e = NE - 1;
      pe[r] = E + (size_t)e * H1 + quad * 8;
      ps[r] = PQ + (size_t)s_src[row] * 256 + quad * 8;
      pq[r] = PQ + (size_t)s_dst[row] * 256 + 128 + quad * 8;
    }
    f32x4 acc[4][4];
#pragma unroll
    for (int r = 0; r < 4; ++r)
#pragma unroll
      for (int c = 0; c < 4; ++c) acc[r][c] = (f32x4)0.f;

#pragma unroll
    for (int kk = 0; kk < 4; ++kk) {
      half8 a[4];
#pragma unroll
      for (int r = 0; r < 4; ++r) {
        const half8 e8 = *(const half8*)(pe[r] + kk * 32);
        const half8 p8 = *(const half8*)(ps[r] + kk * 32);
        const half8 q8 = *(const half8*)(pq[r] + kk * 32);
        a[r] = hrelu8(e8 + p8 + q8);
      }
#pragma unroll
      for (int c = 0; c < 4; ++c) {
        const half8 bf = bp[(kk * 4 + c) * 64 + lane];
#pragma unroll
        for (int r = 0; r < 4; ++r)
          acc[r][c] = __builtin_amdgcn_mfma_f32_16x16x32_f16(a[r], bf, acc[r][c], 0, 0, 0);
      }
    }
#pragma unroll
    for (int r = 0; r < 4; ++r) {
      const int erow = w * 64 + r * 16 + quad * 4;
#pragma unroll
      for (int c = 0; c < 4; ++c) {
        const int colL = c * 16 + m15;
        const float bv = s_b[colL];
#pragma unroll
        for (int reg = 0; reg < 4; ++reg) {
          const int e = base + erow + reg;
          float x = acc[r][c][reg] + bv;
          x = fmaxf(x, 0.f);
          if (e >= NE) x = 0.f;
          st_s[c] += x; st_q[c] += x * x;
          // x2 row e lives in E row e's first 64 halves
          if (e < NE) E[(size_t)e * H1 + colL] = (_Float16)x;
        }
      }
    }
  }
  __syncthreads();
#pragma unroll
  for (int c = 0; c < 4; ++c) {
    float a = st_s[c]; a += __shfl_xor(a, 16); a += __shfl_xor(a, 32);
    float b = st_q[c]; b += __shfl_xor(b, 16); b += __shfl_xor(b, 32);
    if (lane < 16) { atomicAdd(&s_sum[c * 16 + m15], a); atomicAdd(&s_sq[c * 16 + m15], b); }
  }
  __syncthreads();
  if (t < 64) {
    p2[t * G2 + bid] = s_sum[t];
    p2[64 * G2 + t * G2 + bid] = s_sq[t];
  }
}

// Finalize BN2, fold into W3/b3
__global__ void k_fin2(const float* __restrict__ p2, const float* __restrict__ g2,
                       const float* __restrict__ be2, const float* __restrict__ W3,
                       const float* __restrict__ b3, float* __restrict__ w3f,
                       float* __restrict__ b3f) {
  __shared__ float tp[64];
  const int t = threadIdx.x;
  if (t < 64) {
    float s = 0.f, q = 0.f;
    const float4* rs = (const float4*)(p2 + t * G2);
    const float4* rq = (const float4*)(p2 + 64 * G2 + t * G2);
#pragma unroll 4
    for (int i = 0; i < G2 / 4; ++i) {
      float4 a = rs[i]; s += a.x + a.y + a.z + a.w;
      float4 b = rq[i]; q += b.x + b.y + b.z + b.w;
    }
    const float inv = 1.0f / (float)NE;
    float mean = s * inv;
    float var = q * inv - mean * mean;
    float sc = g2[t] * rsqrtf(var + EPSBN);
    float tt = be2[t] - mean * sc;
    w3f[t] = sc * W3[t];
    tp[t] = tt * W3[t];
  }
  __syncthreads();
  if (t == 0) {
    float b = b3[0];
    for (int j = 0; j < 64; ++j) b += tp[j];
    b3f[0] = b;
  }
}

// out = tanh(x2 @ w3f + b3f); x2 in E rows (stride 128 halves, cols 0..63)
__global__ __launch_bounds__(256)
void k_out(const unsigned short* __restrict__ x2, const float* __restrict__ w3f,
           const float* __restrict__ b3f, float* __restrict__ out) {
  __shared__ float s_w[64];
  __shared__ float s_b;
  const int t = threadIdx.x;
  if (t < 64) s_w[t] = w3f[t];
  if (t == 0) s_b = b3f[0];
  __syncthreads();
  const int gid = blockIdx.x * 256 + t;
  const int e = gid >> 2, p = gid & 3;
  if (e < NE) {
    const uint4* r = (const uint4*)(x2 + (size_t)e * H1 + p * 16);
    float s = 0.f;
#pragma unroll
    for (int i = 0; i < 2; ++i) {
      const uint4 u = r[i];
      const int jb = p * 16 + i * 8;
      s += h2f(u.x) * s_w[jb + 0] + h2f(u.x >> 16) * s_w[jb + 1];
      s += h2f(u.y) * s_w[jb + 2] + h2f(u.y >> 16) * s_w[jb + 3];
      s += h2f(u.z) * s_w[jb + 4] + h2f(u.z >> 16) * s_w[jb + 5];
      s += h2f(u.w) * s_w[jb + 6] + h2f(u.w >> 16) * s_w[jb + 7];
    }
    s += __shfl_xor(s, 1);
    s += __shfl_xor(s, 2);
    if (p == 0) out[e] = tanhf(s + s_b);
  }
}

extern "C" void kernel_launch(void* const* d_in, const int* in_sizes, int n_in,
                              void* d_out, int out_size, void* d_ws, size_t ws_size,
                              hipStream_t stream) {
  const float* emb  = (const float*)d_in[0];
  const float* grad = (const float*)d_in[1];
  const float* step = (const float*)d_in[2];
  const float* W1   = (const float*)d_in[3];
  const float* b1   = (const float*)d_in[4];
  const float* g1   = (const float*)d_in[5];
  const float* be1  = (const float*)d_in[6];
  const float* W2   = (const float*)d_in[7];
  const float* b2   = (const float*)d_in[8];
  const float* g2   = (const float*)d_in[9];
  const float* be2  = (const float*)d_in[10];
  const float* W3   = (const float*)d_in[11];
  const float* b3   = (const float*)d_in[12];
  const void*  eidx = (const void*)d_in[13];
  float* out = (float*)d_out;

  char* ws = (char*)d_ws;
  _Float16* embh   = (_Float16*)(ws + 0);           // 25,600,000
  _Float16* PQ     = (_Float16*)(ws + 25600000LL);  // 25,600,000
  _Float16* bfragC = (_Float16*)(ws + 51200000LL);  // 65,536
  _Float16* bfragN = (_Float16*)(ws + 51265536LL);  // 131,072
  float*    c0     = (float*)(ws + 51396608LL);     // 512
  float*    w2f    = (float*)(ws + 51397120LL);     // 32,768
  float*    b2f    = (float*)(ws + 51429888LL);     // 256
  float*    w3f    = (float*)(ws + 51430144LL);     // 256
  float*    b3f    = (float*)(ws + 51430400LL);     // 16
  float*    p1     = (float*)(ws + 51500032LL);     // 524,288 (128 x GS x 2)
  float*    p2     = (float*)(ws + 52024320LL);     // 524,288 (64 x G2 x 2)
  _Float16* E      = (_Float16*)(ws + 64000000LL);  // 128,000,000 (x2 in-place)

  k_prep   <<<1,    256, 0, stream>>>(W1, b1, step, c0);
  k_prep16 <<<6250, 256, 0, stream>>>(emb, embh);
  k_prepBC <<<16,   256, 0, stream>>>(W1, bfragC);
  k_prepBN <<<32,   256, 0, stream>>>(W1, bfragN);
  k_node   <<<NTN * 4, 256, 0, stream>>>(embh, bfragN, PQ);
  k_edge   <<<GE,   512, 0, stream>>>(embh, eidx, grad, W1, c0, bfragC, E);
  k_stats  <<<GS,   256, 0, stream>>>(E, PQ, eidx, p1);
  k_fin1   <<<1,    256, 0, stream>>>(p1, g1, be1, W2, b2, w2f, b2f);
  k_layer2 <<<G2,   256, 0, stream>>>(E, PQ, eidx, w2f, b2f, p2);
  k_fin2   <<<1,    128, 0, stream>>>(p2, g2, be2, W3, b3, w3f, b3f);
  k_out    <<<7813, 256, 0, stream>>>((const unsigned short*)E, w3f, b3f, out);
}

// Round 8
// 506.831 us; speedup vs baseline: 1.1103x; 1.1103x over previous
//
#include <hip/hip_runtime.h>

#define NE 500000      // edges
#define DIMK 256       // embedding dim
#define H1 128
#define H2 64
#define EPSBN 1e-5f
#define GE1 768
#define NT1 3907       // layer1 tiles of 128 edges
#define G2 1024
#define NT2 1954       // layer2 tiles of 256 edges

typedef _Float16 half8 __attribute__((ext_vector_type(8)));
typedef float f32x4 __attribute__((ext_vector_type(4)));
typedef unsigned short ushort8 __attribute__((ext_vector_type(8)));

static __device__ __forceinline__ half8 habs8(half8 x) {
  ushort8 u = __builtin_bit_cast(ushort8, x);
  u &= (unsigned short)0x7FFF;
  return __builtin_bit_cast(half8, u);
}
static __device__ __forceinline__ float h2f(unsigned int u) {
  return (float)__builtin_bit_cast(_Float16, (unsigned short)(u & 0xffff));
}

// c0[j] = b1[j] + step @ W1[768:800, j]
__global__ void k_prep(const float* __restrict__ W1, const float* __restrict__ b1,
                       const float* __restrict__ step, float* __restrict__ c0) {
  const int j = threadIdx.x;
  if (j < H1) {
    float a = b1[j];
#pragma unroll
    for (int tt = 0; tt < 32; ++tt) a += step[tt] * W1[(768 + tt) * H1 + j];
    c0[j] = a;
  }
}

// fp32 emb -> fp16
__global__ void k_prep16(const float* __restrict__ emb, _Float16* __restrict__ embh) {
  const int i = (blockIdx.x * 256 + threadIdx.x) * 8;
  const float4 a = *(const float4*)(emb + i);
  const float4 b = *(const float4*)(emb + i + 4);
  half8 h;
  h[0] = (_Float16)a.x; h[1] = (_Float16)a.y; h[2] = (_Float16)a.z; h[3] = (_Float16)a.w;
  h[4] = (_Float16)b.x; h[5] = (_Float16)b.y; h[6] = (_Float16)b.z; h[7] = (_Float16)b.w;
  *(half8*)(embh + i) = h;
}

// Fragment-ordered B for layer1: bfrag[(s*64+kc*8+c)*64*8 + lane*8 + j]
__global__ void k_prepB(const float* __restrict__ W1, _Float16* __restrict__ bfrag) {
  const int g = blockIdx.x * 256 + threadIdx.x;
  const int lane = g & 63, f = g >> 6;
  const int c = f & 7, kc = (f >> 3) & 7, s = f >> 6;
  const int row0 = s * 256 + kc * 32 + (lane >> 4) * 8;
  const int col = c * 16 + (lane & 15);
  half8 h;
#pragma unroll
  for (int j = 0; j < 8; ++j) h[j] = (_Float16)W1[(row0 + j) * H1 + col];
  *(half8*)(bfrag + (size_t)g * 8) = h;
}

// Layer 1: tiles of 128 edges; wave = 32 rows x 128 cols (acc[2][8] = 64 VGPR)
// -> 3 waves/SIMD; explicit next-kc register prefetch of u/v gathers.
__global__ __launch_bounds__(256, 3)
void k_layer1(const _Float16* __restrict__ embh, const void* __restrict__ eidx_raw,
              const float* __restrict__ grad, const float* __restrict__ W1,
              const float* __restrict__ c0, const _Float16* __restrict__ bfrag,
              _Float16* __restrict__ x1, float* __restrict__ p1) {
  __shared__ int s_src[128], s_dst[128];
  __shared__ float s_g[128];
  __shared__ float s_wg[128], s_c0[128], s_sum[128], s_sq[128];

  const int t = threadIdx.x, bid = blockIdx.x;
  const int w = t >> 6, lane = t & 63, quad = lane >> 4, m15 = lane & 15;

  if (t < 128) {
    s_wg[t] = W1[800 * H1 + t];
    s_c0[t] = c0[t];
    s_sum[t] = 0.f; s_sq[t] = 0.f;
  }

  const unsigned* ew = (const unsigned*)eidx_raw;
  const bool is64 = ((ew[1] | ew[3] | ew[5] | ew[7]) == 0u);
  const int* e32 = (const int*)eidx_raw;
  const long long* e64 = (const long long*)eidx_raw;

  float st_s[8] = {0, 0, 0, 0, 0, 0, 0, 0}, st_q[8] = {0, 0, 0, 0, 0, 0, 0, 0};
  const half8* bp = (const half8*)bfrag;

  for (int tile = bid; tile < NT1; tile += GE1) {
    const int base = tile * 128;
    __syncthreads();
    if (t < 128) {
      int e = base + t; if (e >= NE) e = NE - 1;
      if (is64) { s_src[t] = (int)e64[e]; s_dst[t] = (int)e64[NE + e]; }
      else      { s_src[t] = e32[e];      s_dst[t] = e32[NE + e]; }
      s_g[t] = grad[e];
    }
    __syncthreads();

    const int row0 = w * 32 + m15;
    const _Float16* pu0 = embh + (size_t)s_src[row0] * DIMK + quad * 8;
    const _Float16* pv0 = embh + (size_t)s_dst[row0] * DIMK + quad * 8;
    const _Float16* pu1 = embh + (size_t)s_src[row0 + 16] * DIMK + quad * 8;
    const _Float16* pv1 = embh + (size_t)s_dst[row0 + 16] * DIMK + quad * 8;

    f32x4 acc[2][8];
#pragma unroll
    for (int r = 0; r < 2; ++r)
#pragma unroll
      for (int c = 0; c < 8; ++c) acc[r][c] = (f32x4)0.f;

    half8 u0 = *(const half8*)pu0;
    half8 v0 = *(const half8*)pv0;
    half8 u1 = *(const half8*)pu1;
    half8 v1 = *(const half8*)pv1;

#pragma unroll 1
    for (int kc = 0; kc < 8; ++kc) {
      half8 nu0, nv0, nu1, nv1;
      if (kc < 7) {                       // prefetch next k-step's gathers
        nu0 = *(const half8*)(pu0 + (kc + 1) * 32);
        nv0 = *(const half8*)(pv0 + (kc + 1) * 32);
        nu1 = *(const half8*)(pu1 + (kc + 1) * 32);
        nv1 = *(const half8*)(pv1 + (kc + 1) * 32);
      }
      const half8 d0 = habs8(u0 - v0);
      const half8 d1 = habs8(u1 - v1);
#pragma unroll
      for (int c = 0; c < 8; ++c) {
        const half8 bu = bp[(kc * 8 + c) * 64 + lane];
        const half8 bv = bp[(64 + kc * 8 + c) * 64 + lane];
        const half8 bd = bp[(128 + kc * 8 + c) * 64 + lane];
        acc[0][c] = __builtin_amdgcn_mfma_f32_16x16x32_f16(u0, bu, acc[0][c], 0, 0, 0);
        acc[1][c] = __builtin_amdgcn_mfma_f32_16x16x32_f16(u1, bu, acc[1][c], 0, 0, 0);
        acc[0][c] = __builtin_amdgcn_mfma_f32_16x16x32_f16(v0, bv, acc[0][c], 0, 0, 0);
        acc[1][c] = __builtin_amdgcn_mfma_f32_16x16x32_f16(v1, bv, acc[1][c], 0, 0, 0);
        acc[0][c] = __builtin_amdgcn_mfma_f32_16x16x32_f16(d0, bd, acc[0][c], 0, 0, 0);
        acc[1][c] = __builtin_amdgcn_mfma_f32_16x16x32_f16(d1, bd, acc[1][c], 0, 0, 0);
      }
      if (kc < 7) { u0 = nu0; v0 = nv0; u1 = nu1; v1 = nv1; }
    }
    // epilogue: D layout col=lane&15, row=quad*4+reg
#pragma unroll
    for (int r = 0; r < 2; ++r) {
      const int erow = w * 32 + r * 16 + quad * 4;
#pragma unroll
      for (int c = 0; c < 8; ++c) {
        const int colL = c * 16 + m15;
        const float wgv = s_wg[colL], c0v = s_c0[colL];
#pragma unroll
        for (int reg = 0; reg < 4; ++reg) {
          const int e = base + erow + reg;
          float x = acc[r][c][reg] + s_g[erow + reg] * wgv + c0v;
          x = fmaxf(x, 0.f);
          if (e >= NE) x = 0.f;
          st_s[c] += x; st_q[c] += x * x;
          if (e < NE) x1[(size_t)e * H1 + colL] = (_Float16)x;
        }
      }
    }
  }
  __syncthreads();
#pragma unroll
  for (int c = 0; c < 8; ++c) {
    float a = st_s[c]; a += __shfl_xor(a, 16); a += __shfl_xor(a, 32);
    float b = st_q[c]; b += __shfl_xor(b, 16); b += __shfl_xor(b, 32);
    if (lane < 16) { atomicAdd(&s_sum[c * 16 + m15], a); atomicAdd(&s_sq[c * 16 + m15], b); }
  }
  __syncthreads();
  if (t < 128) {
    p1[t * GE1 + bid] = s_sum[t];
    p1[128 * GE1 + t * GE1 + bid] = s_sq[t];
  }
}

// Finalize BN1 stats, fold into W2/b2
__global__ void k_fin1(const float* __restrict__ p1, const float* __restrict__ g1,
                       const float* __restrict__ be1, const float* __restrict__ W2,
                       const float* __restrict__ b2, float* __restrict__ w2f,
                       float* __restrict__ b2f) {
  __shared__ float s1[128], t1[128];
  const int t = threadIdx.x;
  if (t < 128) {
    float s = 0.f, q = 0.f;
    const float4* rs = (const float4*)(p1 + t * GE1);
    const float4* rq = (const float4*)(p1 + 128 * GE1 + t * GE1);
#pragma unroll 4
    for (int i = 0; i < GE1 / 4; ++i) {
      float4 a = rs[i]; s += a.x + a.y + a.z + a.w;
      float4 b = rq[i]; q += b.x + b.y + b.z + b.w;
    }
    const float inv = 1.0f / (float)NE;
    float mean = s * inv;
    float var = q * inv - mean * mean;
    float sc = g1[t] * rsqrtf(var + EPSBN);
    s1[t] = sc; t1[t] = be1[t] - mean * sc;
  }
  __syncthreads();
  for (int i = t; i < H1 * H2; i += 256) w2f[i] = s1[i >> 6] * W2[i];
  if (t < 64) {
    float b = b2[t];
    for (int j = 0; j < 128; ++j) b += t1[j] * W2[j * 64 + t];
    b2f[t] = b;
  }
}

// Layer 2: x2 = relu(x1 @ W2F + b2F); B (16KB) in LDS; 4 waves/SIMD
__global__ __launch_bounds__(256, 4)
void k_layer2(const _Float16* __restrict__ x1, const float* __restrict__ w2f,
              const float* __restrict__ b2f, _Float16* __restrict__ x2,
              float* __restrict__ p2) {
  __shared__ __align__(16) _Float16 b_lds[8192];
  __shared__ float s_b[64], s_sum[64], s_sq[64];
  const int t = threadIdx.x, bid = blockIdx.x;
  const int w = t >> 6, lane = t & 63, quad = lane >> 4, m15 = lane & 15;

  for (int i = t; i < 8192; i += 256) {
    const int j = i & 7, li = (i >> 3) & 63, f = i >> 9;
    const int c = f & 3, kk = f >> 2;
    const int row = kk * 32 + (li >> 4) * 8 + j;
    const int col = c * 16 + (li & 15);
    b_lds[i] = (_Float16)w2f[row * H2 + col];
  }
  if (t < 64) { s_b[t] = b2f[t]; s_sum[t] = 0.f; s_sq[t] = 0.f; }
  __syncthreads();

  float st_s[4] = {0, 0, 0, 0}, st_q[4] = {0, 0, 0, 0};
  const half8* bp = (const half8*)b_lds;

  for (int job = bid; job < NT2; job += G2) {
    const int base = job * 256;
    const _Float16* pa[4];
#pragma unroll
    for (int r = 0; r < 4; ++r) {
      int e = base + w * 64 + r * 16 + m15; if (e >= NE) e = NE - 1;
      pa[r] = x1 + (size_t)e * H1 + quad * 8;
    }
    f32x4 acc[4][4];
#pragma unroll
    for (int r = 0; r < 4; ++r)
#pragma unroll
      for (int c = 0; c < 4; ++c) acc[r][c] = (f32x4)0.f;

#pragma unroll
    for (int kk = 0; kk < 4; ++kk) {
      half8 a[4];
#pragma unroll
      for (int r = 0; r < 4; ++r) a[r] = *(const half8*)(pa[r] + kk * 32);
#pragma unroll
      for (int c = 0; c < 4; ++c) {
        const half8 bf = bp[(kk * 4 + c) * 64 + lane];
#pragma unroll
        for (int r = 0; r < 4; ++r)
          acc[r][c] = __builtin_amdgcn_mfma_f32_16x16x32_f16(a[r], bf, acc[r][c], 0, 0, 0);
      }
    }
#pragma unroll
    for (int r = 0; r < 4; ++r) {
      const int erow = w * 64 + r * 16 + quad * 4;
#pragma unroll
      for (int c = 0; c < 4; ++c) {
        const int colL = c * 16 + m15;
        const float bv = s_b[colL];
#pragma unroll
        for (int reg = 0; reg < 4; ++reg) {
          const int e = base + erow + reg;
          float x = acc[r][c][reg] + bv;
          x = fmaxf(x, 0.f);
          if (e >= NE) x = 0.f;
          st_s[c] += x; st_q[c] += x * x;
          if (e < NE) x2[(size_t)e * H2 + colL] = (_Float16)x;
        }
      }
    }
  }
  __syncthreads();
#pragma unroll
  for (int c = 0; c < 4; ++c) {
    float a = st_s[c]; a += __shfl_xor(a, 16); a += __shfl_xor(a, 32);
    float b = st_q[c]; b += __shfl_xor(b, 16); b += __shfl_xor(b, 32);
    if (lane < 16) { atomicAdd(&s_sum[c * 16 + m15], a); atomicAdd(&s_sq[c * 16 + m15], b); }
  }
  __syncthreads();
  if (t < 64) {
    p2[t * G2 + bid] = s_sum[t];
    p2[64 * G2 + t * G2 + bid] = s_sq[t];
  }
}

// Finalize BN2, fold into W3/b3
__global__ void k_fin2(const float* __restrict__ p2, const float* __restrict__ g2,
                       const float* __restrict__ be2, const float* __restrict__ W3,
                       const float* __restrict__ b3, float* __restrict__ w3f,
                       float* __restrict__ b3f) {
  __shared__ float tp[64];
  const int t = threadIdx.x;
  if (t < 64) {
    float s = 0.f, q = 0.f;
    const float4* rs = (const float4*)(p2 + t * G2);
    const float4* rq = (const float4*)(p2 + 64 * G2 + t * G2);
#pragma unroll 4
    for (int i = 0; i < G2 / 4; ++i) {
      float4 a = rs[i]; s += a.x + a.y + a.z + a.w;
      float4 b = rq[i]; q += b.x + b.y + b.z + b.w;
    }
    const float inv = 1.0f / (float)NE;
    float mean = s * inv;
    float var = q * inv - mean * mean;
    float sc = g2[t] * rsqrtf(var + EPSBN);
    float tt = be2[t] - mean * sc;
    w3f[t] = sc * W3[t];
    tp[t] = tt * W3[t];
  }
  __syncthreads();
  if (t == 0) {
    float b = b3[0];
    for (int j = 0; j < 64; ++j) b += tp[j];
    b3f[0] = b;
  }
}

// out = tanh(x2 @ w3f + b3f); 4 lanes per edge
__global__ __launch_bounds__(256)
void k_out(const unsigned short* __restrict__ x2, const float* __restrict__ w3f,
           const float* __restrict__ b3f, float* __restrict__ out) {
  __shared__ float s_w[64];
  __shared__ float s_b;
  const int t = threadIdx.x;
  if (t < 64) s_w[t] = w3f[t];
  if (t == 0) s_b = b3f[0];
  __syncthreads();
  const int gid = blockIdx.x * 256 + t;
  const int e = gid >> 2, p = gid & 3;
  if (e < NE) {
    const uint4* r = (const uint4*)(x2 + (size_t)e * H2 + p * 16);
    float s = 0.f;
#pragma unroll
    for (int i = 0; i < 2; ++i) {
      const uint4 u = r[i];
      const int jb = p * 16 + i * 8;
      s += h2f(u.x) * s_w[jb + 0] + h2f(u.x >> 16) * s_w[jb + 1];
      s += h2f(u.y) * s_w[jb + 2] + h2f(u.y >> 16) * s_w[jb + 3];
      s += h2f(u.z) * s_w[jb + 4] + h2f(u.z >> 16) * s_w[jb + 5];
      s += h2f(u.w) * s_w[jb + 6] + h2f(u.w >> 16) * s_w[jb + 7];
    }
    s += __shfl_xor(s, 1);
    s += __shfl_xor(s, 2);
    if (p == 0) out[e] = tanhf(s + s_b);
  }
}

extern "C" void kernel_launch(void* const* d_in, const int* in_sizes, int n_in,
                              void* d_out, int out_size, void* d_ws, size_t ws_size,
                              hipStream_t stream) {
  const float* emb  = (const float*)d_in[0];
  const float* grad = (const float*)d_in[1];
  const float* step = (const float*)d_in[2];
  const float* W1   = (const float*)d_in[3];
  const float* b1   = (const float*)d_in[4];
  const float* g1   = (const float*)d_in[5];
  const float* be1  = (const float*)d_in[6];
  const float* W2   = (const float*)d_in[7];
  const float* b2   = (const float*)d_in[8];
  const float* g2   = (const float*)d_in[9];
  const float* be2  = (const float*)d_in[10];
  const float* W3   = (const float*)d_in[11];
  const float* b3   = (const float*)d_in[12];
  const void*  eidx = (const void*)d_in[13];
  float* out = (float*)d_out;

  char* ws = (char*)d_ws;
  // region A (64 MB): embh+bfrag+c0+p1 live through fin1; x2 overwrites in layer2
  _Float16* embh  = (_Float16*)(ws + 0);           // 25,600,000
  _Float16* x2    = (_Float16*)(ws + 0);           // 64,000,000 (after fin1)
  _Float16* bfrag = (_Float16*)(ws + 25600000LL);  // 196,608
  float*    c0    = (float*)(ws + 25796608LL);     // 512
  float*    p1    = (float*)(ws + 30000000LL);     // 786,432 (128 x 768 x 2)
  _Float16* x1    = (_Float16*)(ws + 64000000LL);  // 128,000,000
  float*    p2    = (float*)(ws + 192000000LL);    // 524,288 (64 x 1024 x 2)
  float*    w2f   = (float*)(ws + 192524288LL);    // 32,768
  float*    b2f   = (float*)(ws + 192557056LL);    // 256
  float*    w3f   = (float*)(ws + 192557312LL);    // 256
  float*    b3f   = (float*)(ws + 192557568LL);    // 16

  k_prep   <<<1,    256, 0, stream>>>(W1, b1, step, c0);
  k_prep16 <<<6250, 256, 0, stream>>>(emb, embh);
  k_prepB  <<<48,   256, 0, stream>>>(W1, bfrag);
  k_layer1 <<<GE1,  256, 0, stream>>>(embh, eidx, grad, W1, c0, bfrag, x1, p1);
  k_fin1   <<<1,    256, 0, stream>>>(p1, g1, be1, W2, b2, w2f, b2f);
  k_layer2 <<<G2,   256, 0, stream>>>(x1, w2f, b2f, x2, p2);
  k_fin2   <<<1,    128, 0, stream>>>(p2, g2, be2, W3, b3, w3f, b3f);
  k_out    <<<7813, 256, 0, stream>>>((const unsigned short*)x2, w3f, b3f, out);
}

// Round 9
// 467.133 us; speedup vs baseline: 1.2047x; 1.0850x over previous
//
#include <hip/hip_runtime.h>

#define NE 500000      // edges
#define DIMK 256       // embedding dim
#define H1 128
#define H2 64
#define EPSBN 1e-5f
#define GRIDL 512
#define NT 1954        // tiles of 256 edges

typedef _Float16 half8 __attribute__((ext_vector_type(8)));
typedef float f32x4 __attribute__((ext_vector_type(4)));
typedef unsigned short ushort8 __attribute__((ext_vector_type(8)));

static __device__ __forceinline__ half8 habs8(half8 x) {
  ushort8 u = __builtin_bit_cast(ushort8, x);
  u &= (unsigned short)0x7FFF;
  return __builtin_bit_cast(half8, u);
}
static __device__ __forceinline__ float h2f(unsigned int u) {
  return (float)__builtin_bit_cast(_Float16, (unsigned short)(u & 0xffff));
}

// c0[j] = b1[j] + step @ W1[768:800, j]
__global__ void k_prep(const float* __restrict__ W1, const float* __restrict__ b1,
                       const float* __restrict__ step, float* __restrict__ c0) {
  const int j = threadIdx.x;
  if (j < H1) {
    float a = b1[j];
#pragma unroll
    for (int tt = 0; tt < 32; ++tt) a += step[tt] * W1[(768 + tt) * H1 + j];
    c0[j] = a;
  }
}

// fp32 emb -> fp16
__global__ void k_prep16(const float* __restrict__ emb, _Float16* __restrict__ embh) {
  const int i = (blockIdx.x * 256 + threadIdx.x) * 8;
  const float4 a = *(const float4*)(emb + i);
  const float4 b = *(const float4*)(emb + i + 4);
  half8 h;
  h[0] = (_Float16)a.x; h[1] = (_Float16)a.y; h[2] = (_Float16)a.z; h[3] = (_Float16)a.w;
  h[4] = (_Float16)b.x; h[5] = (_Float16)b.y; h[6] = (_Float16)b.z; h[7] = (_Float16)b.w;
  *(half8*)(embh + i) = h;
}

// Fragment-ordered B for layer1: frag gidx = s*64 + kc*8 + c; 512 halves each
__global__ void k_prepB(const float* __restrict__ W1, _Float16* __restrict__ bfrag) {
  const int g = blockIdx.x * 256 + threadIdx.x;
  const int lane = g & 63, f = g >> 6;
  const int c = f & 7, kc = (f >> 3) & 7, s = f >> 6;
  const int row0 = s * 256 + kc * 32 + (lane >> 4) * 8;
  const int col = c * 16 + (lane & 15);
  half8 h;
#pragma unroll
  for (int j = 0; j < 8; ++j) h[j] = (_Float16)W1[(row0 + j) * H1 + col];
  *(half8*)(bfrag + (size_t)g * 8) = h;
}

// Layer 1: 512-thread blocks (8 waves x 32 rows = 256-edge tile), full 128 cols.
// B staged per-kc into LDS (double-buffered, 1-kc lookahead): each B byte read
// from L2 once per BLOCK per tile (r4 read it once per WAVE -> 4x traffic).
__global__ __launch_bounds__(512, 4)
void k_layer1(const _Float16* __restrict__ embh, const void* __restrict__ eidx_raw,
              const float* __restrict__ grad, const float* __restrict__ W1,
              const float* __restrict__ c0, const _Float16* __restrict__ bfrag,
              _Float16* __restrict__ x1, float* __restrict__ p1) {
  __shared__ __align__(16) _Float16 sB[2][12288];   // 2 x 24 KB kc-chunks
  __shared__ int s_src[256], s_dst[256];
  __shared__ float s_g[256];
  __shared__ float s_wg[128], s_c0[128], s_sum[128], s_sq[128];

  const int t = threadIdx.x, bid = blockIdx.x;
  const int w = t >> 6, lane = t & 63, quad = lane >> 4, m15 = lane & 15;

  if (t < 128) {
    s_wg[t] = W1[800 * H1 + t];
    s_c0[t] = c0[t];
    s_sum[t] = 0.f; s_sq[t] = 0.f;
  }

  const unsigned* ew = (const unsigned*)eidx_raw;
  const bool is64 = ((ew[1] | ew[3] | ew[5] | ew[7]) == 0u);
  const int* e32 = (const int*)eidx_raw;
  const long long* e64 = (const long long*)eidx_raw;

  float st_s[8] = {0, 0, 0, 0, 0, 0, 0, 0}, st_q[8] = {0, 0, 0, 0, 0, 0, 0, 0};

  // staging: wave w stages frags f0..f0+2 (f = s*8 + c); 8 waves x 3 = 24 frags/kc
  const int f0 = w * 3;
  int goff[3];                     // kc-independent global offset (halves)
#pragma unroll
  for (int i = 0; i < 3; ++i) {
    const int f = f0 + i, s = f >> 3, c = f & 7;
    goff[i] = (s * 64 + c) * 512 + lane * 8;
  }

  for (int tile = bid; tile < NT; tile += GRIDL) {
    const int base = tile * 256;
    __syncthreads();                       // prev tile fully done (s_g, sB reads)
    if (t < 256) {
      int e = base + t; if (e >= NE) e = NE - 1;
      if (is64) { s_src[t] = (int)e64[e]; s_dst[t] = (int)e64[NE + e]; }
      else      { s_src[t] = e32[e];      s_dst[t] = e32[NE + e]; }
      s_g[t] = grad[e];
    }
    // stage kc=0 into buf0 (independent of s_src)
    {
      uint4 stg[3];
#pragma unroll
      for (int i = 0; i < 3; ++i) stg[i] = *(const uint4*)(bfrag + goff[i]);
#pragma unroll
      for (int i = 0; i < 3; ++i) *(uint4*)&sB[0][(f0 + i) * 512 + lane * 8] = stg[i];
    }
    __syncthreads();                       // s_src ready AND buf0 staged

    const int row0 = w * 32 + m15;
    const _Float16* pu0 = embh + (size_t)s_src[row0] * DIMK + quad * 8;
    const _Float16* pv0 = embh + (size_t)s_dst[row0] * DIMK + quad * 8;
    const _Float16* pu1 = embh + (size_t)s_src[row0 + 16] * DIMK + quad * 8;
    const _Float16* pv1 = embh + (size_t)s_dst[row0 + 16] * DIMK + quad * 8;

    f32x4 acc[2][8];
#pragma unroll
    for (int r = 0; r < 2; ++r)
#pragma unroll
      for (int c = 0; c < 8; ++c) acc[r][c] = (f32x4)0.f;

#pragma unroll 1
    for (int kc = 0; kc < 8; ++kc) {
      uint4 stg[3];
      if (kc < 7) {                        // issue next kc's B loads early
#pragma unroll
        for (int i = 0; i < 3; ++i)
          stg[i] = *(const uint4*)(bfrag + goff[i] + (kc + 1) * 4096);
      }
      const half8 u0 = *(const half8*)(pu0 + kc * 32);
      const half8 v0 = *(const half8*)(pv0 + kc * 32);
      const half8 u1 = *(const half8*)(pu1 + kc * 32);
      const half8 v1 = *(const half8*)(pv1 + kc * 32);
      const half8 d0 = habs8(u0 - v0);
      const half8 d1 = habs8(u1 - v1);
      const half8* sb = (const half8*)sB[kc & 1];
#pragma unroll
      for (int c = 0; c < 8; ++c) {
        const half8 bu = sb[c * 64 + lane];
        const half8 bv = sb[(8 + c) * 64 + lane];
        const half8 bd = sb[(16 + c) * 64 + lane];
        acc[0][c] = __builtin_amdgcn_mfma_f32_16x16x32_f16(u0, bu, acc[0][c], 0, 0, 0);
        acc[1][c] = __builtin_amdgcn_mfma_f32_16x16x32_f16(u1, bu, acc[1][c], 0, 0, 0);
        acc[0][c] = __builtin_amdgcn_mfma_f32_16x16x32_f16(v0, bv, acc[0][c], 0, 0, 0);
        acc[1][c] = __builtin_amdgcn_mfma_f32_16x16x32_f16(v1, bv, acc[1][c], 0, 0, 0);
        acc[0][c] = __builtin_amdgcn_mfma_f32_16x16x32_f16(d0, bd, acc[0][c], 0, 0, 0);
        acc[1][c] = __builtin_amdgcn_mfma_f32_16x16x32_f16(d1, bd, acc[1][c], 0, 0, 0);
      }
      if (kc < 7) {
        const int b = (kc + 1) & 1;
#pragma unroll
        for (int i = 0; i < 3; ++i) *(uint4*)&sB[b][(f0 + i) * 512 + lane * 8] = stg[i];
      }
      __syncthreads();                     // next buf staged; current buf free
    }
    // epilogue: D layout col=lane&15, row=quad*4+reg
#pragma unroll
    for (int r = 0; r < 2; ++r) {
      const int erow = w * 32 + r * 16 + quad * 4;
#pragma unroll
      for (int c = 0; c < 8; ++c) {
        const int colL = c * 16 + m15;
        const float wgv = s_wg[colL], c0v = s_c0[colL];
#pragma unroll
        for (int reg = 0; reg < 4; ++reg) {
          const int e = base + erow + reg;
          float x = acc[r][c][reg] + s_g[erow + reg] * wgv + c0v;
          x = fmaxf(x, 0.f);
          if (e >= NE) x = 0.f;
          st_s[c] += x; st_q[c] += x * x;
          if (e < NE) x1[(size_t)e * H1 + colL] = (_Float16)x;
        }
      }
    }
  }
  __syncthreads();
#pragma unroll
  for (int c = 0; c < 8; ++c) {
    float a = st_s[c]; a += __shfl_xor(a, 16); a += __shfl_xor(a, 32);
    float b = st_q[c]; b += __shfl_xor(b, 16); b += __shfl_xor(b, 32);
    if (lane < 16) { atomicAdd(&s_sum[c * 16 + m15], a); atomicAdd(&s_sq[c * 16 + m15], b); }
  }
  __syncthreads();
  if (t < 128) {
    p1[t * GRIDL + bid] = s_sum[t];
    p1[128 * GRIDL + t * GRIDL + bid] = s_sq[t];
  }
}

// Finalize BN1 stats, fold into W2/b2
__global__ void k_fin1(const float* __restrict__ p1, const float* __restrict__ g1,
                       const float* __restrict__ be1, const float* __restrict__ W2,
                       const float* __restrict__ b2, float* __restrict__ w2f,
                       float* __restrict__ b2f) {
  __shared__ float s1[128], t1[128];
  const int t = threadIdx.x;
  if (t < 128) {
    float s = 0.f, q = 0.f;
    const float4* rs = (const float4*)(p1 + t * GRIDL);
    const float4* rq = (const float4*)(p1 + 128 * GRIDL + t * GRIDL);
#pragma unroll 4
    for (int i = 0; i < GRIDL / 4; ++i) {
      float4 a = rs[i]; s += a.x + a.y + a.z + a.w;
      float4 b = rq[i]; q += b.x + b.y + b.z + b.w;
    }
    const float inv = 1.0f / (float)NE;
    float mean = s * inv;
    float var = q * inv - mean * mean;
    float sc = g1[t] * rsqrtf(var + EPSBN);
    s1[t] = sc; t1[t] = be1[t] - mean * sc;
  }
  __syncthreads();
  for (int i = t; i < H1 * H2; i += 256) w2f[i] = s1[i >> 6] * W2[i];
  if (t < 64) {
    float b = b2[t];
    for (int j = 0; j < 128; ++j) b += t1[j] * W2[j * 64 + t];
    b2f[t] = b;
  }
}

// Layer 2 (r4 exact): x2 = relu(x1 @ W2F + b2F), B (16KB) resident in LDS
__global__ __launch_bounds__(256, 2)
void k_layer2(const _Float16* __restrict__ x1, const float* __restrict__ w2f,
              const float* __restrict__ b2f, _Float16* __restrict__ x2,
              float* __restrict__ p2) {
  __shared__ __align__(16) _Float16 b_lds[8192];
  __shared__ float s_b[64], s_sum[64], s_sq[64];
  const int t = threadIdx.x, bid = blockIdx.x;
  const int w = t >> 6, lane = t & 63, quad = lane >> 4, m15 = lane & 15;

  for (int i = t; i < 8192; i += 256) {
    const int j = i & 7, li = (i >> 3) & 63, f = i >> 9;
    const int c = f & 3, kk = f >> 2;
    const int row = kk * 32 + (li >> 4) * 8 + j;
    const int col = c * 16 + (li & 15);
    b_lds[i] = (_Float16)w2f[row * H2 + col];
  }
  if (t < 64) { s_b[t] = b2f[t]; s_sum[t] = 0.f; s_sq[t] = 0.f; }
  __syncthreads();

  float st_s[4] = {0, 0, 0, 0}, st_q[4] = {0, 0, 0, 0};
  const half8* bp = (const half8*)b_lds;

  for (int job = bid; job < NT; job += GRIDL) {
    const int base = job * 256;
    const _Float16* pa[4];
#pragma unroll
    for (int r = 0; r < 4; ++r) {
      int e = base + w * 64 + r * 16 + m15; if (e >= NE) e = NE - 1;
      pa[r] = x1 + (size_t)e * H1 + quad * 8;
    }
    f32x4 acc[4][4];
#pragma unroll
    for (int r = 0; r < 4; ++r)
#pragma unroll
      for (int c = 0; c < 4; ++c) acc[r][c] = (f32x4)0.f;

#pragma unroll
    for (int kk = 0; kk < 4; ++kk) {
      half8 a[4];
#pragma unroll
      for (int r = 0; r < 4; ++r) a[r] = *(const half8*)(pa[r] + kk * 32);
#pragma unroll
      for (int c = 0; c < 4; ++c) {
        const half8 bf = bp[(kk * 4 + c) * 64 + lane];
#pragma unroll
        for (int r = 0; r < 4; ++r)
          acc[r][c] = __builtin_amdgcn_mfma_f32_16x16x32_f16(a[r], bf, acc[r][c], 0, 0, 0);
      }
    }
#pragma unroll
    for (int r = 0; r < 4; ++r) {
      const int erow = w * 64 + r * 16 + quad * 4;
#pragma unroll
      for (int c = 0; c < 4; ++c) {
        const int colL = c * 16 + m15;
        const float bv = s_b[colL];
#pragma unroll
        for (int reg = 0; reg < 4; ++reg) {
          const int e = base + erow + reg;
          float x = acc[r][c][reg] + bv;
          x = fmaxf(x, 0.f);
          if (e >= NE) x = 0.f;
          st_s[c] += x; st_q[c] += x * x;
          if (e < NE) x2[(size_t)e * H2 + colL] = (_Float16)x;
        }
      }
    }
  }
  __syncthreads();
#pragma unroll
  for (int c = 0; c < 4; ++c) {
    float a = st_s[c]; a += __shfl_xor(a, 16); a += __shfl_xor(a, 32);
    float b = st_q[c]; b += __shfl_xor(b, 16); b += __shfl_xor(b, 32);
    if (lane < 16) { atomicAdd(&s_sum[c * 16 + m15], a); atomicAdd(&s_sq[c * 16 + m15], b); }
  }
  __syncthreads();
  if (t < 64) {
    p2[t * GRIDL + bid] = s_sum[t];
    p2[64 * GRIDL + t * GRIDL + bid] = s_sq[t];
  }
}

// Finalize BN2, fold into W3/b3
__global__ void k_fin2(const float* __restrict__ p2, const float* __restrict__ g2,
                       const float* __restrict__ be2, const float* __restrict__ W3,
                       const float* __restrict__ b3, float* __restrict__ w3f,
                       float* __restrict__ b3f) {
  __shared__ float tp[64];
  const int t = threadIdx.x;
  if (t < 64) {
    float s = 0.f, q = 0.f;
    const float4* rs = (const float4*)(p2 + t * GRIDL);
    const float4* rq = (const float4*)(p2 + 64 * GRIDL + t * GRIDL);
#pragma unroll 4
    for (int i = 0; i < GRIDL / 4; ++i) {
      float4 a = rs[i]; s += a.x + a.y + a.z + a.w;
      float4 b = rq[i]; q += b.x + b.y + b.z + b.w;
    }
    const float inv = 1.0f / (float)NE;
    float mean = s * inv;
    float var = q * inv - mean * mean;
    float sc = g2[t] * rsqrtf(var + EPSBN);
    float tt = be2[t] - mean * sc;
    w3f[t] = sc * W3[t];
    tp[t] = tt * W3[t];
  }
  __syncthreads();
  if (t == 0) {
    float b = b3[0];
    for (int j = 0; j < 64; ++j) b += tp[j];
    b3f[0] = b;
  }
}

// out = tanh(x2 @ w3f + b3f); 4 lanes per edge
__global__ __launch_bounds__(256)
void k_out(const unsigned short* __restrict__ x2, const float* __restrict__ w3f,
           const float* __restrict__ b3f, float* __restrict__ out) {
  __shared__ float s_w[64];
  __shared__ float s_b;
  const int t = threadIdx.x;
  if (t < 64) s_w[t] = w3f[t];
  if (t == 0) s_b = b3f[0];
  __syncthreads();
  const int gid = blockIdx.x * 256 + t;
  const int e = gid >> 2, p = gid & 3;
  if (e < NE) {
    const uint4* r = (const uint4*)(x2 + (size_t)e * H2 + p * 16);
    float s = 0.f;
#pragma unroll
    for (int i = 0; i < 2; ++i) {
      const uint4 u = r[i];
      const int jb = p * 16 + i * 8;
      s += h2f(u.x) * s_w[jb + 0] + h2f(u.x >> 16) * s_w[jb + 1];
      s += h2f(u.y) * s_w[jb + 2] + h2f(u.y >> 16) * s_w[jb + 3];
      s += h2f(u.z) * s_w[jb + 4] + h2f(u.z >> 16) * s_w[jb + 5];
      s += h2f(u.w) * s_w[jb + 6] + h2f(u.w >> 16) * s_w[jb + 7];
    }
    s += __shfl_xor(s, 1);
    s += __shfl_xor(s, 2);
    if (p == 0) out[e] = tanhf(s + s_b);
  }
}

extern "C" void kernel_launch(void* const* d_in, const int* in_sizes, int n_in,
                              void* d_out, int out_size, void* d_ws, size_t ws_size,
                              hipStream_t stream) {
  const float* emb  = (const float*)d_in[0];
  const float* grad = (const float*)d_in[1];
  const float* step = (const float*)d_in[2];
  const float* W1   = (const float*)d_in[3];
  const float* b1   = (const float*)d_in[4];
  const float* g1   = (const float*)d_in[5];
  const float* be1  = (const float*)d_in[6];
  const float* W2   = (const float*)d_in[7];
  const float* b2   = (const float*)d_in[8];
  const float* g2   = (const float*)d_in[9];
  const float* be2  = (const float*)d_in[10];
  const float* W3   = (const float*)d_in[11];
  const float* b3   = (const float*)d_in[12];
  const void*  eidx = (const void*)d_in[13];
  float* out = (float*)d_out;

  char* ws = (char*)d_ws;
  // region A (64MB): embh + bfrag + c0 during layer1; x2 overwrites in layer2
  _Float16* embh  = (_Float16*)(ws + 0);           // 25,600,000
  _Float16* x2    = (_Float16*)(ws + 0);           // 64,000,000 (after fin1)
  _Float16* bfrag = (_Float16*)(ws + 25600000LL);  // 196,608
  float*    c0    = (float*)(ws + 25796608LL);     // 512
  _Float16* x1    = (_Float16*)(ws + 64000000LL);  // 128,000,000
  float* p1  = (float*)(ws + 192000000LL);         // 524,288 (128 x 512 x 2)
  float* p2  = (float*)(ws + 192524288LL);         // 262,144 (64 x 512 x 2)
  float* w2f = (float*)(ws + 192786432LL);         // 32,768
  float* b2f = (float*)(ws + 192819200LL);         // 256
  float* w3f = (float*)(ws + 192819456LL);         // 256
  float* b3f = (float*)(ws + 192819712LL);         // 16

  k_prep   <<<1,    256, 0, stream>>>(W1, b1, step, c0);
  k_prep16 <<<6250, 256, 0, stream>>>(emb, embh);
  k_prepB  <<<48,   256, 0, stream>>>(W1, bfrag);
  k_layer1 <<<GRIDL,512, 0, stream>>>(embh, eidx, grad, W1, c0, bfrag, x1, p1);
  k_fin1   <<<1,    256, 0, stream>>>(p1, g1, be1, W2, b2, w2f, b2f);
  k_layer2 <<<GRIDL,256, 0, stream>>>(x1, w2f, b2f, x2, p2);
  k_fin2   <<<1,    128, 0, stream>>>(p2, g2, be2, W3, b3, w3f, b3f);
  k_out    <<<7813, 256, 0, stream>>>((const unsigned short*)x2, w3f, b3f, out);
}